// Round 3
// baseline (437.760 us; speedup 1.0000x reference)
//
#include <hip/hip_runtime.h>
#include <cstdint>
#include <cstddef>

// ---------------------------------------------------------------------------
// COAMultiHeadAttention: MHA forward on gfx950.
//   B=2, T=2048, D=1024, H=16, HD=64.
//   detect-dtype -> mask-summary -> fused QKV GEMM (128x128, global_load_lds,
//   XOR-swizzled LDS) -> V transpose -> flash attention (mask fast-path,
//   pre-transposed V, swizzled LDS) -> out GEMM (64x128).
//   External floats may be f32 or bf16 (runtime detect; bf16 confirmed hot).
// ---------------------------------------------------------------------------

using frag8 = __attribute__((ext_vector_type(8))) short;   // 8 x bf16
using f32x4 = __attribute__((ext_vector_type(4))) float;
using int4v = __attribute__((ext_vector_type(4))) int;

#define MFMA16(a, b, c) __builtin_amdgcn_mfma_f32_16x16x32_bf16((a), (b), (c), 0, 0, 0)

#define T_SEQ 2048
#define D_MOD 1024

__device__ __forceinline__ float bf2f(unsigned short s) {
    unsigned u = ((unsigned)s) << 16;
    return __builtin_bit_cast(float, u);
}
__device__ __forceinline__ short f2bf(float f) {
    unsigned u = __builtin_bit_cast(unsigned, f);
    u += 0x7fffu + ((u >> 16) & 1u);
    return (short)(u >> 16);
}

// async 16B global -> LDS (wave-uniform LDS base + lane*16)
__device__ __forceinline__ void async16(const void* gptr, void* lptr) {
    __builtin_amdgcn_global_load_lds(
        (const __attribute__((address_space(1))) void*)gptr,
        (__attribute__((address_space(3))) void*)lptr, 16, 0, 0);
}

// 8 f32 -> 8 bf16 -> one 16B LDS store (f32 fallback path)
__device__ __forceinline__ void stage_cvt(short* dst, const float* src) {
    float4 lo = *(const float4*)src;
    float4 hi = *(const float4*)(src + 4);
    union { int4v v; short s[8]; } pk;
    pk.s[0] = f2bf(lo.x); pk.s[1] = f2bf(lo.y); pk.s[2] = f2bf(lo.z); pk.s[3] = f2bf(lo.w);
    pk.s[4] = f2bf(hi.x); pk.s[5] = f2bf(hi.y); pk.s[6] = f2bf(hi.z); pk.s[7] = f2bf(hi.w);
    *(int4v*)dst = pk.v;
}

// ---------------------------------------------------------------------------
// Dtype detection (f32 mantissa shorts have uniform bf16-exponent fields).
// ---------------------------------------------------------------------------
__global__ void detect_dtype(const unsigned short* __restrict__ q, int* __restrict__ flag) {
    if (threadIdx.x == 0) {
        int f = 0;
        for (int i = 0; i < 256; ++i) {
            const int e = (q[i] >> 7) & 0xFF;
            f |= (e >= 0xC0) ? 1 : 0;
        }
        *flag = f;   // 1 => external floats are f32
    }
}

// ---------------------------------------------------------------------------
// Mask summary: summ[b][qt][kt] = 1 iff the 64x64 mask tile is all nonzero.
// grid (32 qt, 2 b), 256 threads; each thread ANDs 16 ints per k-tile.
// ---------------------------------------------------------------------------
__global__ __launch_bounds__(256) void mask_summary(const int* __restrict__ mask,
                                                    int* __restrict__ summ) {
    const int b = blockIdx.y, qt = blockIdx.x, tid = threadIdx.x;
    const int wave = tid >> 6;
    __shared__ int red[4];
    const int row = tid >> 2;          // 0..63
    const int c4  = (tid & 3) * 16;    // 0,16,32,48
    const int* mb = mask + ((size_t)b * T_SEQ + qt * 64 + row) * T_SEQ;
    for (int kt = 0; kt < 32; ++kt) {
        const int* pp = mb + kt * 64 + c4;
        int4v a = *(const int4v*)pp;
        int4v c = *(const int4v*)(pp + 4);
        int4v d = *(const int4v*)(pp + 8);
        int4v e = *(const int4v*)(pp + 12);
        const bool anyzero = !(a[0] && a[1] && a[2] && a[3] &&
                               c[0] && c[1] && c[2] && c[3] &&
                               d[0] && d[1] && d[2] && d[3] &&
                               e[0] && e[1] && e[2] && e[3]);
        unsigned long long bal = __ballot(anyzero);
        if ((tid & 63) == 0) red[wave] = (bal != 0ull) ? 1 : 0;
        __syncthreads();
        if (tid == 0)
            summ[((b * 32 + qt) * 32) + kt] = !(red[0] | red[1] | red[2] | red[3]);
        __syncthreads();
    }
}

// ---------------------------------------------------------------------------
// V transpose: Vp [B,T,H,64] -> Vt [B,H,64,T]. 64x64 LDS tile, coalesced.
// ---------------------------------------------------------------------------
__global__ __launch_bounds__(256) void transpose_v(const unsigned short* __restrict__ Vp,
                                                   unsigned short* __restrict__ Vt) {
    __shared__ short t[64][72];
    const int tid = threadIdx.x;
    const int b = blockIdx.z, h = blockIdx.y, t0 = blockIdx.x * 64;
    const int r0 = tid >> 3, c0 = (tid & 7) * 8;
    const size_t ib = ((size_t)b * T_SEQ + t0) * D_MOD + h * 64;
    *(int4v*)&t[r0][c0]      = *(const int4v*)&Vp[ib + (size_t)r0 * D_MOD + c0];
    *(int4v*)&t[r0 + 32][c0] = *(const int4v*)&Vp[ib + (size_t)(r0 + 32) * D_MOD + c0];
    __syncthreads();
    const size_t ob = ((size_t)(b * 16 + h) * 64) * T_SEQ + t0;
    union { int4v v; short s[8]; } o0, o1;
#pragma unroll
    for (int j = 0; j < 8; ++j) { o0.s[j] = t[c0 + j][r0]; o1.s[j] = t[c0 + j][r0 + 32]; }
    *(int4v*)&Vt[ob + (size_t)r0 * T_SEQ + c0]        = o0.v;
    *(int4v*)&Vt[ob + (size_t)(r0 + 32) * T_SEQ + c0] = o1.v;
}

// ---------------------------------------------------------------------------
// GEMM core: Y[M,1024] = X[M,1024] @ W[1024,1024]^T + bias. BMx128 tile,
// BK=64, global_load_lds staging, XOR-swizzled LDS (chunk col ^= row&7).
// ---------------------------------------------------------------------------
template<int BM>
__device__ __forceinline__ void gemm_core(
    short* sA, short* sB,
    const void* __restrict__ Xv, const void* __restrict__ Wv,
    const void* __restrict__ biasv, void* __restrict__ Yv,
    bool xf, bool wf, bool yf)
{
    constexpr int K = 1024, N = 1024;
    constexpr int MT = BM / 32;
    const int tid  = threadIdx.x;
    const int wave = tid >> 6;
    const int lane = tid & 63;
    const int g    = lane >> 4;
    const int r    = lane & 15;
    const int m0   = blockIdx.y * BM;
    const int n0   = blockIdx.x * 128;
    const int wm   = (wave >> 1) * (BM / 2);
    const int wn   = (wave & 1) * 64;

    f32x4 acc[MT][4] = {};

    for (int k0 = 0; k0 < K; k0 += 64) {
        if (!xf) {
            const unsigned short* Xb = (const unsigned short*)Xv;
#pragma unroll
            for (int i = 0; i < BM / 32; ++i) {
                const int cb = (i * 4 + wave) * 64;
                const int c  = cb + lane;
                const int row = c >> 3, cg = (c & 7) ^ (row & 7);
                async16(&Xb[(size_t)(m0 + row) * K + k0 + cg * 8], &sA[cb * 8]);
            }
        } else {
            const float* Xf = (const float*)Xv;
#pragma unroll
            for (int i = 0; i < BM / 32; ++i) {
                const int cb = (i * 4 + wave) * 64;
                const int c  = cb + lane;
                const int row = c >> 3, cg = (c & 7) ^ (row & 7);
                stage_cvt(&sA[c * 8], &Xf[(size_t)(m0 + row) * K + k0 + cg * 8]);
            }
        }
        if (!wf) {
            const unsigned short* Wb = (const unsigned short*)Wv;
#pragma unroll
            for (int i = 0; i < 4; ++i) {
                const int cb = (i * 4 + wave) * 64;
                const int c  = cb + lane;
                const int row = c >> 3, cg = (c & 7) ^ (row & 7);
                async16(&Wb[(size_t)(n0 + row) * K + k0 + cg * 8], &sB[cb * 8]);
            }
        } else {
            const float* Wf = (const float*)Wv;
#pragma unroll
            for (int i = 0; i < 4; ++i) {
                const int cb = (i * 4 + wave) * 64;
                const int c  = cb + lane;
                const int row = c >> 3, cg = (c & 7) ^ (row & 7);
                stage_cvt(&sB[c * 8], &Wf[(size_t)(n0 + row) * K + k0 + cg * 8]);
            }
        }
        __syncthreads();   // drains vmcnt (global_load_lds) + lgkm
#pragma unroll
        for (int ks = 0; ks < 2; ++ks) {
            frag8 a[MT], bfr[4];
#pragma unroll
            for (int mt = 0; mt < MT; ++mt) {
                const int row = wm + mt * 16 + r;
                a[mt] = *(const frag8*)&sA[row * 64 + ((ks * 4 + g) ^ (r & 7)) * 8];
            }
#pragma unroll
            for (int nt = 0; nt < 4; ++nt) {
                const int row = wn + nt * 16 + r;
                bfr[nt] = *(const frag8*)&sB[row * 64 + ((ks * 4 + g) ^ (r & 7)) * 8];
            }
#pragma unroll
            for (int mt = 0; mt < MT; ++mt)
#pragma unroll
                for (int nt = 0; nt < 4; ++nt)
                    acc[mt][nt] = MFMA16(a[mt], bfr[nt], acc[mt][nt]);
        }
        __syncthreads();
    }

#pragma unroll
    for (int nt = 0; nt < 4; ++nt) {
        const int n = n0 + wn + nt * 16 + r;
        const float bv = wf ? ((const float*)biasv)[n]
                            : bf2f(((const unsigned short*)biasv)[n]);
#pragma unroll
        for (int mt = 0; mt < MT; ++mt) {
#pragma unroll
            for (int reg = 0; reg < 4; ++reg) {
                const int m = m0 + wm + mt * 16 + g * 4 + reg;
                const float val = acc[mt][nt][reg] + bv;
                if (yf) ((float*)Yv)[(size_t)m * N + n] = val;
                else    ((unsigned short*)Yv)[(size_t)m * N + n] = (unsigned short)f2bf(val);
            }
        }
    }
}

__global__ __launch_bounds__(256) void gemm_qkv(
    const void* q, const void* k, const void* v,
    const void* wq, const void* wk, const void* wv,
    const void* bq, const void* bk, const void* bv,
    unsigned short* Qp, unsigned short* Kp, unsigned short* Vp,
    const int* __restrict__ dflag)
{
    __shared__ short sA[128 * 64];
    __shared__ short sB[128 * 64];
    const bool f = dflag[0] != 0;
    const void* X; const void* W; const void* Bv; unsigned short* Y;
    if (blockIdx.z == 0)      { X = q; W = wq; Bv = bq; Y = Qp; }
    else if (blockIdx.z == 1) { X = k; W = wk; Bv = bk; Y = Kp; }
    else                      { X = v; W = wv; Bv = bv; Y = Vp; }
    gemm_core<128>(sA, sB, X, W, Bv, Y, f, f, false);
}

__global__ __launch_bounds__(256) void gemm_out(
    const unsigned short* att, const void* wo, const void* bo,
    void* out, const int* __restrict__ dflag)
{
    __shared__ short sA[64 * 64];
    __shared__ short sB[128 * 64];
    const bool f = dflag[0] != 0;
    gemm_core<64>(sA, sB, att, wo, bo, out, false, f, f);
}

// ---------------------------------------------------------------------------
// Flash attention: block = (b, h, 64 q-rows), 4 waves x 16 q-rows.
// Pre-transposed V; XOR-swizzled LDS; mask fast-path via tile summary.
// Softmax in log2 domain (exp2), INF-free.
// ---------------------------------------------------------------------------
__global__ __launch_bounds__(256) void flash_attn(
    const unsigned short* __restrict__ Qp, const unsigned short* __restrict__ Kp,
    const unsigned short* __restrict__ Vt, const int* __restrict__ mask,
    const int* __restrict__ summ, unsigned short* __restrict__ att)
{
    __shared__ short sQ[64 * 64];
    __shared__ short sK[64 * 64];
    __shared__ short sVt[64 * 64];
    __shared__ short sP[4][16][72];
    __shared__ int sFlags[32];

    const int tid  = threadIdx.x;
    const int wave = tid >> 6;
    const int lane = tid & 63;
    const int g    = lane >> 4;
    const int r    = lane & 15;
    const int b    = blockIdx.z;
    const int h    = blockIdx.y;
    const int q0   = blockIdx.x * 64;

    const size_t base   = ((size_t)b * T_SEQ) * D_MOD + (size_t)h * 64;
    const size_t vtbase = ((size_t)(b * 16 + h) * 64) * T_SEQ;

#pragma unroll
    for (int i = 0; i < 2; ++i) {
        const int cb = (i * 4 + wave) * 64;
        const int c  = cb + lane;
        const int row = c >> 3, cg = (c & 7) ^ (row & 7);
        async16(&Qp[base + (size_t)(q0 + row) * D_MOD + cg * 8], &sQ[cb * 8]);
    }
    if (tid < 32) sFlags[tid] = summ[((b * 32 + (q0 >> 6)) * 32) + tid];
    __syncthreads();

    frag8 aq0 = *(const frag8*)&sQ[(wave * 16 + r) * 64 + ((0 + g) ^ (r & 7)) * 8];
    frag8 aq1 = *(const frag8*)&sQ[(wave * 16 + r) * 64 + ((4 + g) ^ (r & 7)) * 8];

    float run_m[4], run_l[4];
    f32x4 accO[4];
#pragma unroll
    for (int i = 0; i < 4; ++i) {
        run_m[i] = -1e30f;
        run_l[i] = 0.f;
        accO[i]  = f32x4{0.f, 0.f, 0.f, 0.f};
    }

    const float scale2 = 0.125f * 1.44269504f;  // 1/sqrt(64) * log2(e)
    const int* mrow = mask + ((size_t)b * T_SEQ) * T_SEQ;
    const int qrow = q0 + wave * 16;

    for (int kt = 0, idx = 0; kt < T_SEQ; kt += 64, ++idx) {
#pragma unroll
        for (int i = 0; i < 2; ++i) {
            const int cb = (i * 4 + wave) * 64;
            const int c  = cb + lane;
            const int row = c >> 3, cg = (c & 7) ^ (row & 7);
            async16(&Kp[base + (size_t)(kt + row) * D_MOD + cg * 8], &sK[cb * 8]);
            async16(&Vt[vtbase + (size_t)row * T_SEQ + kt + cg * 8], &sVt[cb * 8]);
        }
        __syncthreads();

        // ---- S = Q K^T (log2-domain scale applied below) ----
        f32x4 s[4];
#pragma unroll
        for (int ct = 0; ct < 4; ++ct) {
            const int row = ct * 16 + r;
            frag8 bk0 = *(const frag8*)&sK[row * 64 + ((0 + g) ^ (r & 7)) * 8];
            frag8 bk1 = *(const frag8*)&sK[row * 64 + ((4 + g) ^ (r & 7)) * 8];
            f32x4 z = f32x4{0.f, 0.f, 0.f, 0.f};
            z = MFMA16(aq0, bk0, z);
            s[ct] = MFMA16(aq1, bk1, z);
        }

        float p[4][4];
        float tmax[4] = {-1e30f, -1e30f, -1e30f, -1e30f};
        if (sFlags[idx]) {           // all-ones tile: no mask loads
#pragma unroll
            for (int ct = 0; ct < 4; ++ct)
#pragma unroll
                for (int reg = 0; reg < 4; ++reg) {
                    const float v = s[ct][reg] * scale2;
                    p[ct][reg] = v;
                    tmax[reg] = fmaxf(tmax[reg], v);
                }
        } else {
#pragma unroll
            for (int ct = 0; ct < 4; ++ct)
#pragma unroll
                for (int reg = 0; reg < 4; ++reg) {
                    float v = s[ct][reg] * scale2;
                    const int mk = mrow[(size_t)(qrow + g * 4 + reg) * T_SEQ + kt + ct * 16 + r];
                    v = (mk == 0) ? -1e30f : v;
                    p[ct][reg] = v;
                    tmax[reg] = fmaxf(tmax[reg], v);
                }
        }
#pragma unroll
        for (int reg = 0; reg < 4; ++reg) {
            float t = tmax[reg];
            t = fmaxf(t, __shfl_xor(t, 1));
            t = fmaxf(t, __shfl_xor(t, 2));
            t = fmaxf(t, __shfl_xor(t, 4));
            t = fmaxf(t, __shfl_xor(t, 8));
            tmax[reg] = t;
        }

        float alpha[4], rsum[4];
#pragma unroll
        for (int reg = 0; reg < 4; ++reg) {
            const float nm = fmaxf(run_m[reg], tmax[reg]);
            alpha[reg] = exp2f(run_m[reg] - nm);
            run_m[reg] = nm;
            float srow = 0.f;
#pragma unroll
            for (int ct = 0; ct < 4; ++ct) {
                const float e = exp2f(p[ct][reg] - nm);
                p[ct][reg] = e;
                srow += e;
            }
            rsum[reg] = srow;
        }
#pragma unroll
        for (int reg = 0; reg < 4; ++reg) {
            float t = rsum[reg];
            t += __shfl_xor(t, 1);
            t += __shfl_xor(t, 2);
            t += __shfl_xor(t, 4);
            t += __shfl_xor(t, 8);
            run_l[reg] = run_l[reg] * alpha[reg] + t;
        }

        // ---- P: C-layout -> LDS (A-layout source) ----
#pragma unroll
        for (int ct = 0; ct < 4; ++ct)
#pragma unroll
            for (int reg = 0; reg < 4; ++reg)
                sP[wave][g * 4 + reg][ct * 16 + r] = f2bf(p[ct][reg]);
        __syncthreads();

#pragma unroll
        for (int dt = 0; dt < 4; ++dt)
#pragma unroll
            for (int reg = 0; reg < 4; ++reg)
                accO[dt][reg] *= alpha[reg];

#pragma unroll
        for (int ks = 0; ks < 2; ++ks) {
            frag8 ap = *(const frag8*)&sP[wave][r][ks * 32 + g * 8];
#pragma unroll
            for (int dt = 0; dt < 4; ++dt) {
                const int row = dt * 16 + r;
                frag8 bv = *(const frag8*)&sVt[row * 64 + ((ks * 4 + g) ^ (r & 7)) * 8];
                accO[dt] = MFMA16(ap, bv, accO[dt]);
            }
        }
        __syncthreads();   // PV done before restaging sK/sVt/sP
    }

#pragma unroll
    for (int dt = 0; dt < 4; ++dt) {
#pragma unroll
        for (int reg = 0; reg < 4; ++reg) {
            const float o = accO[dt][reg] / run_l[reg];
            const int qq = q0 + wave * 16 + g * 4 + reg;
            att[((size_t)b * T_SEQ + qq) * D_MOD + h * 64 + dt * 16 + r] =
                (unsigned short)f2bf(o);
        }
    }
}

// ---------------------------------------------------------------------------
extern "C" void kernel_launch(void* const* d_in, const int* in_sizes, int n_in,
                              void* d_out, int out_size, void* d_ws, size_t ws_size,
                              hipStream_t stream) {
    const void* query = d_in[0];
    const void* key   = d_in[1];
    const void* value = d_in[2];
    const int*  mask  = (const int*)d_in[3];
    const void* wq = d_in[4];  const void* bq = d_in[5];
    const void* wk = d_in[6];  const void* bk = d_in[7];
    const void* wv = d_in[8];  const void* bv = d_in[9];
    const void* wo = d_in[10]; const void* bo = d_in[11];

    const size_t TN = (size_t)2 * T_SEQ * D_MOD;   // 4,194,304 elements

    unsigned short* Qp  = (unsigned short*)d_ws;
    unsigned short* Kp  = Qp + TN;
    unsigned short* Vp  = Kp + TN;
    unsigned short* Vt  = Vp + TN;
    unsigned short* att = Vp;                       // alias: Vp dead after transpose
    int* flagp = (int*)(Vt + TN);
    int* summp = flagp + 1;

    detect_dtype<<<1, 64, 0, stream>>>((const unsigned short*)query, flagp);
    mask_summary<<<dim3(32, 2), 256, 0, stream>>>(mask, summp);

    gemm_qkv<<<dim3(8, 32, 3), 256, 0, stream>>>(query, key, value, wq, wk, wv,
                                                 bq, bk, bv, Qp, Kp, Vp, flagp);

    transpose_v<<<dim3(32, 16, 2), 256, 0, stream>>>(Vp, Vt);

    flash_attn<<<dim3(32, 16, 2), 256, 0, stream>>>(Qp, Kp, Vt, mask, summp, att);

    gemm_out<<<dim3(8, 64), 256, 0, stream>>>(att, wo, bo, d_out, flagp);
}

// Round 7
// 435.288 us; speedup vs baseline: 1.0057x; 1.0057x over previous
//
#include <hip/hip_runtime.h>
#include <cstdint>
#include <cstddef>

// ---------------------------------------------------------------------------
// COAMultiHeadAttention: MHA forward on gfx950.  [R7 = R3 verbatim re-anchor]
//   B=2, T=2048, D=1024, H=16, HD=64.
//   detect-dtype -> mask-summary -> fused QKV GEMM (128x128, global_load_lds,
//   XOR-swizzled LDS) -> V transpose -> flash attention (mask fast-path,
//   pre-transposed V, swizzled LDS) -> out GEMM (64x128).
//   External floats may be f32 or bf16 (runtime detect; bf16 confirmed hot).
// ---------------------------------------------------------------------------

using frag8 = __attribute__((ext_vector_type(8))) short;   // 8 x bf16
using f32x4 = __attribute__((ext_vector_type(4))) float;
using int4v = __attribute__((ext_vector_type(4))) int;

#define MFMA16(a, b, c) __builtin_amdgcn_mfma_f32_16x16x32_bf16((a), (b), (c), 0, 0, 0)

#define T_SEQ 2048
#define D_MOD 1024

__device__ __forceinline__ float bf2f(unsigned short s) {
    unsigned u = ((unsigned)s) << 16;
    return __builtin_bit_cast(float, u);
}
__device__ __forceinline__ short f2bf(float f) {
    unsigned u = __builtin_bit_cast(unsigned, f);
    u += 0x7fffu + ((u >> 16) & 1u);
    return (short)(u >> 16);
}

// async 16B global -> LDS (wave-uniform LDS base + lane*16)
__device__ __forceinline__ void async16(const void* gptr, void* lptr) {
    __builtin_amdgcn_global_load_lds(
        (const __attribute__((address_space(1))) void*)gptr,
        (__attribute__((address_space(3))) void*)lptr, 16, 0, 0);
}

// 8 f32 -> 8 bf16 -> one 16B LDS store (f32 fallback path)
__device__ __forceinline__ void stage_cvt(short* dst, const float* src) {
    float4 lo = *(const float4*)src;
    float4 hi = *(const float4*)(src + 4);
    union { int4v v; short s[8]; } pk;
    pk.s[0] = f2bf(lo.x); pk.s[1] = f2bf(lo.y); pk.s[2] = f2bf(lo.z); pk.s[3] = f2bf(lo.w);
    pk.s[4] = f2bf(hi.x); pk.s[5] = f2bf(hi.y); pk.s[6] = f2bf(hi.z); pk.s[7] = f2bf(hi.w);
    *(int4v*)dst = pk.v;
}

// ---------------------------------------------------------------------------
// Dtype detection (f32 mantissa shorts have uniform bf16-exponent fields).
// ---------------------------------------------------------------------------
__global__ void detect_dtype(const unsigned short* __restrict__ q, int* __restrict__ flag) {
    if (threadIdx.x == 0) {
        int f = 0;
        for (int i = 0; i < 256; ++i) {
            const int e = (q[i] >> 7) & 0xFF;
            f |= (e >= 0xC0) ? 1 : 0;
        }
        *flag = f;   // 1 => external floats are f32
    }
}

// ---------------------------------------------------------------------------
// Mask summary: summ[b][qt][kt] = 1 iff the 64x64 mask tile is all nonzero.
// grid (32 qt, 2 b), 256 threads; each thread ANDs 16 ints per k-tile.
// ---------------------------------------------------------------------------
__global__ __launch_bounds__(256) void mask_summary(const int* __restrict__ mask,
                                                    int* __restrict__ summ) {
    const int b = blockIdx.y, qt = blockIdx.x, tid = threadIdx.x;
    const int wave = tid >> 6;
    __shared__ int red[4];
    const int row = tid >> 2;          // 0..63
    const int c4  = (tid & 3) * 16;    // 0,16,32,48
    const int* mb = mask + ((size_t)b * T_SEQ + qt * 64 + row) * T_SEQ;
    for (int kt = 0; kt < 32; ++kt) {
        const int* pp = mb + kt * 64 + c4;
        int4v a = *(const int4v*)pp;
        int4v c = *(const int4v*)(pp + 4);
        int4v d = *(const int4v*)(pp + 8);
        int4v e = *(const int4v*)(pp + 12);
        const bool anyzero = !(a[0] && a[1] && a[2] && a[3] &&
                               c[0] && c[1] && c[2] && c[3] &&
                               d[0] && d[1] && d[2] && d[3] &&
                               e[0] && e[1] && e[2] && e[3]);
        unsigned long long bal = __ballot(anyzero);
        if ((tid & 63) == 0) red[wave] = (bal != 0ull) ? 1 : 0;
        __syncthreads();
        if (tid == 0)
            summ[((b * 32 + qt) * 32) + kt] = !(red[0] | red[1] | red[2] | red[3]);
        __syncthreads();
    }
}

// ---------------------------------------------------------------------------
// V transpose: Vp [B,T,H,64] -> Vt [B,H,64,T]. 64x64 LDS tile, coalesced.
// ---------------------------------------------------------------------------
__global__ __launch_bounds__(256) void transpose_v(const unsigned short* __restrict__ Vp,
                                                   unsigned short* __restrict__ Vt) {
    __shared__ short t[64][72];
    const int tid = threadIdx.x;
    const int b = blockIdx.z, h = blockIdx.y, t0 = blockIdx.x * 64;
    const int r0 = tid >> 3, c0 = (tid & 7) * 8;
    const size_t ib = ((size_t)b * T_SEQ + t0) * D_MOD + h * 64;
    *(int4v*)&t[r0][c0]      = *(const int4v*)&Vp[ib + (size_t)r0 * D_MOD + c0];
    *(int4v*)&t[r0 + 32][c0] = *(const int4v*)&Vp[ib + (size_t)(r0 + 32) * D_MOD + c0];
    __syncthreads();
    const size_t ob = ((size_t)(b * 16 + h) * 64) * T_SEQ + t0;
    union { int4v v; short s[8]; } o0, o1;
#pragma unroll
    for (int j = 0; j < 8; ++j) { o0.s[j] = t[c0 + j][r0]; o1.s[j] = t[c0 + j][r0 + 32]; }
    *(int4v*)&Vt[ob + (size_t)r0 * T_SEQ + c0]        = o0.v;
    *(int4v*)&Vt[ob + (size_t)(r0 + 32) * T_SEQ + c0] = o1.v;
}

// ---------------------------------------------------------------------------
// GEMM core: Y[M,1024] = X[M,1024] @ W[1024,1024]^T + bias. BMx128 tile,
// BK=64, global_load_lds staging, XOR-swizzled LDS (chunk col ^= row&7).
// ---------------------------------------------------------------------------
template<int BM>
__device__ __forceinline__ void gemm_core(
    short* sA, short* sB,
    const void* __restrict__ Xv, const void* __restrict__ Wv,
    const void* __restrict__ biasv, void* __restrict__ Yv,
    bool xf, bool wf, bool yf)
{
    constexpr int K = 1024, N = 1024;
    constexpr int MT = BM / 32;
    const int tid  = threadIdx.x;
    const int wave = tid >> 6;
    const int lane = tid & 63;
    const int g    = lane >> 4;
    const int r    = lane & 15;
    const int m0   = blockIdx.y * BM;
    const int n0   = blockIdx.x * 128;
    const int wm   = (wave >> 1) * (BM / 2);
    const int wn   = (wave & 1) * 64;

    f32x4 acc[MT][4] = {};

    for (int k0 = 0; k0 < K; k0 += 64) {
        if (!xf) {
            const unsigned short* Xb = (const unsigned short*)Xv;
#pragma unroll
            for (int i = 0; i < BM / 32; ++i) {
                const int cb = (i * 4 + wave) * 64;
                const int c  = cb + lane;
                const int row = c >> 3, cg = (c & 7) ^ (row & 7);
                async16(&Xb[(size_t)(m0 + row) * K + k0 + cg * 8], &sA[cb * 8]);
            }
        } else {
            const float* Xf = (const float*)Xv;
#pragma unroll
            for (int i = 0; i < BM / 32; ++i) {
                const int cb = (i * 4 + wave) * 64;
                const int c  = cb + lane;
                const int row = c >> 3, cg = (c & 7) ^ (row & 7);
                stage_cvt(&sA[c * 8], &Xf[(size_t)(m0 + row) * K + k0 + cg * 8]);
            }
        }
        if (!wf) {
            const unsigned short* Wb = (const unsigned short*)Wv;
#pragma unroll
            for (int i = 0; i < 4; ++i) {
                const int cb = (i * 4 + wave) * 64;
                const int c  = cb + lane;
                const int row = c >> 3, cg = (c & 7) ^ (row & 7);
                async16(&Wb[(size_t)(n0 + row) * K + k0 + cg * 8], &sB[cb * 8]);
            }
        } else {
            const float* Wf = (const float*)Wv;
#pragma unroll
            for (int i = 0; i < 4; ++i) {
                const int cb = (i * 4 + wave) * 64;
                const int c  = cb + lane;
                const int row = c >> 3, cg = (c & 7) ^ (row & 7);
                stage_cvt(&sB[c * 8], &Wf[(size_t)(n0 + row) * K + k0 + cg * 8]);
            }
        }
        __syncthreads();   // drains vmcnt (global_load_lds) + lgkm
#pragma unroll
        for (int ks = 0; ks < 2; ++ks) {
            frag8 a[MT], bfr[4];
#pragma unroll
            for (int mt = 0; mt < MT; ++mt) {
                const int row = wm + mt * 16 + r;
                a[mt] = *(const frag8*)&sA[row * 64 + ((ks * 4 + g) ^ (r & 7)) * 8];
            }
#pragma unroll
            for (int nt = 0; nt < 4; ++nt) {
                const int row = wn + nt * 16 + r;
                bfr[nt] = *(const frag8*)&sB[row * 64 + ((ks * 4 + g) ^ (r & 7)) * 8];
            }
#pragma unroll
            for (int mt = 0; mt < MT; ++mt)
#pragma unroll
                for (int nt = 0; nt < 4; ++nt)
                    acc[mt][nt] = MFMA16(a[mt], bfr[nt], acc[mt][nt]);
        }
        __syncthreads();
    }

#pragma unroll
    for (int nt = 0; nt < 4; ++nt) {
        const int n = n0 + wn + nt * 16 + r;
        const float bv = wf ? ((const float*)biasv)[n]
                            : bf2f(((const unsigned short*)biasv)[n]);
#pragma unroll
        for (int mt = 0; mt < MT; ++mt) {
#pragma unroll
            for (int reg = 0; reg < 4; ++reg) {
                const int m = m0 + wm + mt * 16 + g * 4 + reg;
                const float val = acc[mt][nt][reg] + bv;
                if (yf) ((float*)Yv)[(size_t)m * N + n] = val;
                else    ((unsigned short*)Yv)[(size_t)m * N + n] = (unsigned short)f2bf(val);
            }
        }
    }
}

__global__ __launch_bounds__(256) void gemm_qkv(
    const void* q, const void* k, const void* v,
    const void* wq, const void* wk, const void* wv,
    const void* bq, const void* bk, const void* bv,
    unsigned short* Qp, unsigned short* Kp, unsigned short* Vp,
    const int* __restrict__ dflag)
{
    __shared__ short sA[128 * 64];
    __shared__ short sB[128 * 64];
    const bool f = dflag[0] != 0;
    const void* X; const void* W; const void* Bv; unsigned short* Y;
    if (blockIdx.z == 0)      { X = q; W = wq; Bv = bq; Y = Qp; }
    else if (blockIdx.z == 1) { X = k; W = wk; Bv = bk; Y = Kp; }
    else                      { X = v; W = wv; Bv = bv; Y = Vp; }
    gemm_core<128>(sA, sB, X, W, Bv, Y, f, f, false);
}

__global__ __launch_bounds__(256) void gemm_out(
    const unsigned short* att, const void* wo, const void* bo,
    void* out, const int* __restrict__ dflag)
{
    __shared__ short sA[64 * 64];
    __shared__ short sB[128 * 64];
    const bool f = dflag[0] != 0;
    gemm_core<64>(sA, sB, att, wo, bo, out, false, f, f);
}

// ---------------------------------------------------------------------------
// Flash attention: block = (b, h, 64 q-rows), 4 waves x 16 q-rows.
// Pre-transposed V; XOR-swizzled LDS; mask fast-path via tile summary.
// Softmax in log2 domain (exp2), INF-free.
// ---------------------------------------------------------------------------
__global__ __launch_bounds__(256) void flash_attn(
    const unsigned short* __restrict__ Qp, const unsigned short* __restrict__ Kp,
    const unsigned short* __restrict__ Vt, const int* __restrict__ mask,
    const int* __restrict__ summ, unsigned short* __restrict__ att)
{
    __shared__ short sQ[64 * 64];
    __shared__ short sK[64 * 64];
    __shared__ short sVt[64 * 64];
    __shared__ short sP[4][16][72];
    __shared__ int sFlags[32];

    const int tid  = threadIdx.x;
    const int wave = tid >> 6;
    const int lane = tid & 63;
    const int g    = lane >> 4;
    const int r    = lane & 15;
    const int b    = blockIdx.z;
    const int h    = blockIdx.y;
    const int q0   = blockIdx.x * 64;

    const size_t base   = ((size_t)b * T_SEQ) * D_MOD + (size_t)h * 64;
    const size_t vtbase = ((size_t)(b * 16 + h) * 64) * T_SEQ;

#pragma unroll
    for (int i = 0; i < 2; ++i) {
        const int cb = (i * 4 + wave) * 64;
        const int c  = cb + lane;
        const int row = c >> 3, cg = (c & 7) ^ (row & 7);
        async16(&Qp[base + (size_t)(q0 + row) * D_MOD + cg * 8], &sQ[cb * 8]);
    }
    if (tid < 32) sFlags[tid] = summ[((b * 32 + (q0 >> 6)) * 32) + tid];
    __syncthreads();

    frag8 aq0 = *(const frag8*)&sQ[(wave * 16 + r) * 64 + ((0 + g) ^ (r & 7)) * 8];
    frag8 aq1 = *(const frag8*)&sQ[(wave * 16 + r) * 64 + ((4 + g) ^ (r & 7)) * 8];

    float run_m[4], run_l[4];
    f32x4 accO[4];
#pragma unroll
    for (int i = 0; i < 4; ++i) {
        run_m[i] = -1e30f;
        run_l[i] = 0.f;
        accO[i]  = f32x4{0.f, 0.f, 0.f, 0.f};
    }

    const float scale2 = 0.125f * 1.44269504f;  // 1/sqrt(64) * log2(e)
    const int* mrow = mask + ((size_t)b * T_SEQ) * T_SEQ;
    const int qrow = q0 + wave * 16;

    for (int kt = 0, idx = 0; kt < T_SEQ; kt += 64, ++idx) {
#pragma unroll
        for (int i = 0; i < 2; ++i) {
            const int cb = (i * 4 + wave) * 64;
            const int c  = cb + lane;
            const int row = c >> 3, cg = (c & 7) ^ (row & 7);
            async16(&Kp[base + (size_t)(kt + row) * D_MOD + cg * 8], &sK[cb * 8]);
            async16(&Vt[vtbase + (size_t)row * T_SEQ + kt + cg * 8], &sVt[cb * 8]);
        }
        __syncthreads();

        // ---- S = Q K^T (log2-domain scale applied below) ----
        f32x4 s[4];
#pragma unroll
        for (int ct = 0; ct < 4; ++ct) {
            const int row = ct * 16 + r;
            frag8 bk0 = *(const frag8*)&sK[row * 64 + ((0 + g) ^ (r & 7)) * 8];
            frag8 bk1 = *(const frag8*)&sK[row * 64 + ((4 + g) ^ (r & 7)) * 8];
            f32x4 z = f32x4{0.f, 0.f, 0.f, 0.f};
            z = MFMA16(aq0, bk0, z);
            s[ct] = MFMA16(aq1, bk1, z);
        }

        float p[4][4];
        float tmax[4] = {-1e30f, -1e30f, -1e30f, -1e30f};
        if (sFlags[idx]) {           // all-ones tile: no mask loads
#pragma unroll
            for (int ct = 0; ct < 4; ++ct)
#pragma unroll
                for (int reg = 0; reg < 4; ++reg) {
                    const float v = s[ct][reg] * scale2;
                    p[ct][reg] = v;
                    tmax[reg] = fmaxf(tmax[reg], v);
                }
        } else {
#pragma unroll
            for (int ct = 0; ct < 4; ++ct)
#pragma unroll
                for (int reg = 0; reg < 4; ++reg) {
                    float v = s[ct][reg] * scale2;
                    const int mk = mrow[(size_t)(qrow + g * 4 + reg) * T_SEQ + kt + ct * 16 + r];
                    v = (mk == 0) ? -1e30f : v;
                    p[ct][reg] = v;
                    tmax[reg] = fmaxf(tmax[reg], v);
                }
        }
#pragma unroll
        for (int reg = 0; reg < 4; ++reg) {
            float t = tmax[reg];
            t = fmaxf(t, __shfl_xor(t, 1));
            t = fmaxf(t, __shfl_xor(t, 2));
            t = fmaxf(t, __shfl_xor(t, 4));
            t = fmaxf(t, __shfl_xor(t, 8));
            tmax[reg] = t;
        }

        float alpha[4], rsum[4];
#pragma unroll
        for (int reg = 0; reg < 4; ++reg) {
            const float nm = fmaxf(run_m[reg], tmax[reg]);
            alpha[reg] = exp2f(run_m[reg] - nm);
            run_m[reg] = nm;
            float srow = 0.f;
#pragma unroll
            for (int ct = 0; ct < 4; ++ct) {
                const float e = exp2f(p[ct][reg] - nm);
                p[ct][reg] = e;
                srow += e;
            }
            rsum[reg] = srow;
        }
#pragma unroll
        for (int reg = 0; reg < 4; ++reg) {
            float t = rsum[reg];
            t += __shfl_xor(t, 1);
            t += __shfl_xor(t, 2);
            t += __shfl_xor(t, 4);
            t += __shfl_xor(t, 8);
            run_l[reg] = run_l[reg] * alpha[reg] + t;
        }

        // ---- P: C-layout -> LDS (A-layout source) ----
#pragma unroll
        for (int ct = 0; ct < 4; ++ct)
#pragma unroll
            for (int reg = 0; reg < 4; ++reg)
                sP[wave][g * 4 + reg][ct * 16 + r] = f2bf(p[ct][reg]);
        __syncthreads();

#pragma unroll
        for (int dt = 0; dt < 4; ++dt)
#pragma unroll
            for (int reg = 0; reg < 4; ++reg)
                accO[dt][reg] *= alpha[reg];

#pragma unroll
        for (int ks = 0; ks < 2; ++ks) {
            frag8 ap = *(const frag8*)&sP[wave][r][ks * 32 + g * 8];
#pragma unroll
            for (int dt = 0; dt < 4; ++dt) {
                const int row = dt * 16 + r;
                frag8 bv = *(const frag8*)&sVt[row * 64 + ((ks * 4 + g) ^ (r & 7)) * 8];
                accO[dt] = MFMA16(ap, bv, accO[dt]);
            }
        }
        __syncthreads();   // PV done before restaging sK/sVt/sP
    }

#pragma unroll
    for (int dt = 0; dt < 4; ++dt) {
#pragma unroll
        for (int reg = 0; reg < 4; ++reg) {
            const float o = accO[dt][reg] / run_l[reg];
            const int qq = q0 + wave * 16 + g * 4 + reg;
            att[((size_t)b * T_SEQ + qq) * D_MOD + h * 64 + dt * 16 + r] =
                (unsigned short)f2bf(o);
        }
    }
}

// ---------------------------------------------------------------------------
extern "C" void kernel_launch(void* const* d_in, const int* in_sizes, int n_in,
                              void* d_out, int out_size, void* d_ws, size_t ws_size,
                              hipStream_t stream) {
    const void* query = d_in[0];
    const void* key   = d_in[1];
    const void* value = d_in[2];
    const int*  mask  = (const int*)d_in[3];
    const void* wq = d_in[4];  const void* bq = d_in[5];
    const void* wk = d_in[6];  const void* bk = d_in[7];
    const void* wv = d_in[8];  const void* bv = d_in[9];
    const void* wo = d_in[10]; const void* bo = d_in[11];

    const size_t TN = (size_t)2 * T_SEQ * D_MOD;   // 4,194,304 elements

    unsigned short* Qp  = (unsigned short*)d_ws;
    unsigned short* Kp  = Qp + TN;
    unsigned short* Vp  = Kp + TN;
    unsigned short* Vt  = Vp + TN;
    unsigned short* att = Vp;                       // alias: Vp dead after transpose
    int* flagp = (int*)(Vt + TN);
    int* summp = flagp + 1;

    detect_dtype<<<1, 64, 0, stream>>>((const unsigned short*)query, flagp);
    mask_summary<<<dim3(32, 2), 256, 0, stream>>>(mask, summp);

    gemm_qkv<<<dim3(8, 32, 3), 256, 0, stream>>>(query, key, value, wq, wk, wv,
                                                 bq, bk, bv, Qp, Kp, Vp, flagp);

    transpose_v<<<dim3(32, 16, 2), 256, 0, stream>>>(Vp, Vt);

    flash_attn<<<dim3(32, 16, 2), 256, 0, stream>>>(Qp, Kp, Vt, mask, summp, att);

    gemm_out<<<dim3(8, 64), 256, 0, stream>>>(att, wo, bo, d_out, flagp);
}